// Round 6
// baseline (1420.033 us; speedup 1.0000x reference)
//
#include <hip/hip_runtime.h>

#define H 512
#define W 512
#define HW (H * W)
#define T 128
#define DECAY 0.8f

typedef float v4f __attribute__((ext_vector_type(4)));
typedef unsigned int v2u __attribute__((ext_vector_type(2)));

__device__ __forceinline__ unsigned int f2bf_rne(float f) {
    unsigned int u = __float_as_uint(f);
    return (u + 0x7fffu + ((u >> 16) & 1u)) >> 16;
}
__device__ __forceinline__ float bf_lo(unsigned int u) {
    return __uint_as_float(u << 16);
}
__device__ __forceinline__ float bf_hi(unsigned int u) {
    return __uint_as_float(u & 0xffff0000u);
}

// ---------------------------------------------------------------------------
// Pass A: pointwise double-EMA scan. float4 lanes, 4-step load batching so
// 4 independent 16B loads are in flight per wave. R stored as packed bf16.
//   p' = .8p + x[t];  r' = .8r + p_old;  Rbuf[t] = r entering step t.
// ---------------------------------------------------------------------------
__global__ __launch_bounds__(256) void scan_chunk(
    const float* __restrict__ x, unsigned int* __restrict__ Rbuf,
    float* __restrict__ state, int t0, int tc)
{
    const int gid = blockIdx.x * 256 + threadIdx.x;      // 0 .. HW/4-1
    const v4f* xp = (const v4f*)x + (size_t)t0 * (HW / 4) + gid;
    v2u* rp = (v2u*)Rbuf + gid;
    v4f* st = (v4f*)state;

    v4f p, r;
    if (t0 == 0) {
        p = (v4f)0.f; r = (v4f)0.f;
    } else {
        p = st[gid];
        r = st[HW / 4 + gid];
    }

#define SCAN_STEP(xv)                                                        \
    {                                                                        \
        v2u pk;                                                              \
        pk.x = f2bf_rne(r.x) | (f2bf_rne(r.y) << 16);                        \
        pk.y = f2bf_rne(r.z) | (f2bf_rne(r.w) << 16);                        \
        rp[(size_t)t * (HW / 4)] = pk;                                       \
        v4f rn = DECAY * r + p;                                              \
        p = DECAY * p + (xv);                                                \
        r = rn;                                                              \
        ++t;                                                                 \
    }

    int t = 0;
    const int t4 = tc & ~3;
    for (; t < t4;) {
        v4f x0 = __builtin_nontemporal_load(&xp[(size_t)(t + 0) * (HW / 4)]);
        v4f x1 = __builtin_nontemporal_load(&xp[(size_t)(t + 1) * (HW / 4)]);
        v4f x2 = __builtin_nontemporal_load(&xp[(size_t)(t + 2) * (HW / 4)]);
        v4f x3 = __builtin_nontemporal_load(&xp[(size_t)(t + 3) * (HW / 4)]);
        SCAN_STEP(x0); SCAN_STEP(x1); SCAN_STEP(x2); SCAN_STEP(x3);
    }
    for (; t < tc;) {
        v4f xv = __builtin_nontemporal_load(&xp[(size_t)t * (HW / 4)]);
        SCAN_STEP(xv);
    }
#undef SCAN_STEP

    st[gid] = p;
    st[HW / 4 + gid] = r;
}

// ---------------------------------------------------------------------------
// Pass B: 9x9 conv, zero pad 4, bf16 input / fp32 output.
// Tile 256 wide x 16 tall. Thread: i = tid&63 -> 4-wide col run, j = tid>>6 ->
// 4-tall patch. A wave (64 lanes) = ONE region row per ds_read: 64 lanes x
// contiguous 8B -> conflict-free. Register-rotating rows: each thread reads
// its 12 input rows once, feeding up to 4 pending output rows.
// acc[4][4]=16 VGPR; __launch_bounds__(256,8) caps VGPR at 64 -> 32 waves/CU.
// ---------------------------------------------------------------------------
#define BX 256
#define BY 16
#define RGROWS 24     // 16 + 8 halo
#define RSTRE 272     // LDS row stride in bf16 elems (544 B)
#define RCHUNK 66     // 4-elem (8 B) chunks per row (264 elems used)

__global__ __launch_bounds__(256, 8) void conv_chunk(
    const unsigned short* __restrict__ Rbuf, const float* __restrict__ wp,
    float* __restrict__ out, int t0)
{
    __shared__ unsigned short reg[RGROWS * RSTRE];   // 13,056 B

    const int tid = threadIdx.x;
    const int tX = blockIdx.x, tY = blockIdx.y, tz = blockIdx.z;
    const int X0 = tX * BX - 4, Y0 = tY * BY - 4;
    const unsigned short* Rp = Rbuf + (size_t)tz * HW;

    float wr[81];                      // wave-uniform -> SGPRs
    #pragma unroll
    for (int q = 0; q < 81; ++q) wr[q] = wp[q];

    // stage region (bf16, 8B chunks; chunks never straddle the image edge)
    #pragma unroll
    for (int k = 0; k < 7; ++k) {
        int e = tid + k * 256;
        if (e < RGROWS * RCHUNK) {
            int rr = e / RCHUNK, c = e - rr * RCHUNK;
            int gy = Y0 + rr, gx = X0 + 4 * c;
            uint2 v = make_uint2(0u, 0u);
            if ((unsigned)gy < H && (unsigned)gx < W)
                v = *(const uint2*)(Rp + (size_t)(gy * W + gx));
            *(uint2*)(&reg[rr * RSTRE + 4 * c]) = v;
        }
    }
    __syncthreads();

    const int i = tid & 63;     // col chunk: region elems 4i..4i+11 window
    const int j = tid >> 6;     // 0..3 -> output rows 4j..4j+3
    const int rbase = 4 * j;

    float acc[4][4];
    #pragma unroll
    for (int a = 0; a < 4; ++a)
        #pragma unroll
        for (int b = 0; b < 4; ++b) acc[a][b] = 0.f;

    #pragma unroll
    for (int r = 0; r < 12; ++r) {
        const unsigned short* rp = &reg[(rbase + r) * RSTRE + 4 * i];
        uint2 va = *(const uint2*)(rp);      // elems 0..3
        uint2 vb = *(const uint2*)(rp + 4);  // elems 4..7
        uint2 vc = *(const uint2*)(rp + 8);  // elems 8..11
        float win[12];
        win[0] = bf_lo(va.x);  win[1] = bf_hi(va.x);
        win[2] = bf_lo(va.y);  win[3] = bf_hi(va.y);
        win[4] = bf_lo(vb.x);  win[5] = bf_hi(vb.x);
        win[6] = bf_lo(vb.y);  win[7] = bf_hi(vb.y);
        win[8] = bf_lo(vc.x);  win[9] = bf_hi(vc.x);
        win[10] = bf_lo(vc.y); win[11] = bf_hi(vc.y);
        #pragma unroll
        for (int oy = 0; oy < 4; ++oy) {
            const int ky = r - oy;                 // compile-time after unroll
            if (ky >= 0 && ky <= 8) {
                #pragma unroll
                for (int kx = 0; kx < 9; ++kx) {
                    float wv = wr[ky * 9 + kx];
                    acc[oy][0] = __builtin_fmaf(wv, win[kx + 0], acc[oy][0]);
                    acc[oy][1] = __builtin_fmaf(wv, win[kx + 1], acc[oy][1]);
                    acc[oy][2] = __builtin_fmaf(wv, win[kx + 2], acc[oy][2]);
                    acc[oy][3] = __builtin_fmaf(wv, win[kx + 3], acc[oy][3]);
                }
            }
        }
    }

    float* op = out + (size_t)(t0 + tz) * HW
                    + (size_t)((tY * BY + 4 * j) * W) + (tX * BX + 4 * i);
    #pragma unroll
    for (int oy = 0; oy < 4; ++oy) {
        v4f v = {acc[oy][0], acc[oy][1], acc[oy][2], acc[oy][3]};
        __builtin_nontemporal_store(v, (v4f*)(op + (size_t)oy * W));
    }
}

// ---------------------------------------------------------------------------
extern "C" void kernel_launch(void* const* d_in, const int* in_sizes, int n_in,
                              void* d_out, int out_size, void* d_ws, size_t ws_size,
                              hipStream_t stream) {
    const float* x = (const float*)d_in[0];  // [128,1,512,512]
    const float* w = (const float*)d_in[1];  // [1,1,9,9]
    float* out = (float*)d_out;              // [128,1,512,512]

    float* state = (float*)d_ws;                               // 2 fp32 planes
    unsigned short* Rbuf = (unsigned short*)(state + 2 * (size_t)HW);

    size_t state_b = 2 * (size_t)HW * sizeof(float);
    size_t plane_b = (size_t)HW * sizeof(unsigned short);
    int maxTc = 1;
    if (ws_size > state_b + plane_b)
        maxTc = (int)((ws_size - state_b) / plane_b);
    int Tc = T;
    if (Tc > maxTc) Tc = maxTc;
    if (Tc < 1) Tc = 1;

    for (int t0 = 0; t0 < T; t0 += Tc) {
        int tc = T - t0;
        if (tc > Tc) tc = Tc;
        scan_chunk<<<dim3(HW / 1024), 256, 0, stream>>>(
            x, (unsigned int*)Rbuf, state, t0, tc);
        conv_chunk<<<dim3(W / BX, H / BY, tc), 256, 0, stream>>>(
            Rbuf, w, out, t0);
    }
}

// Round 7
// 119.152 us; speedup vs baseline: 11.9178x; 11.9178x over previous
//
#include <hip/hip_runtime.h>

#define H 512
#define W 512
#define HW (H * W)
#define T 128
#define DECAY 0.8f

typedef float v4f __attribute__((ext_vector_type(4)));
typedef unsigned int v2u __attribute__((ext_vector_type(2)));

__device__ __forceinline__ unsigned int f2bf_rne(float f) {
    unsigned int u = __float_as_uint(f);
    return (u + 0x7fffu + ((u >> 16) & 1u)) >> 16;
}
__device__ __forceinline__ float bf_lo(unsigned int u) {
    return __uint_as_float(u << 16);
}
__device__ __forceinline__ float bf_hi(unsigned int u) {
    return __uint_as_float(u & 0xffff0000u);
}

// ---------------------------------------------------------------------------
// Pass A: pointwise double-EMA scan. float4 lanes, 4-step load batching so
// 4 independent 16B loads are in flight per wave. R stored as packed bf16.
//   p' = .8p + x[t];  r' = .8r + p_old;  Rbuf[t] = r entering step t.
// (unchanged from round 6 — measured ~25 µs)
// ---------------------------------------------------------------------------
__global__ __launch_bounds__(256) void scan_chunk(
    const float* __restrict__ x, unsigned int* __restrict__ Rbuf,
    float* __restrict__ state, int t0, int tc)
{
    const int gid = blockIdx.x * 256 + threadIdx.x;      // 0 .. HW/4-1
    const v4f* xp = (const v4f*)x + (size_t)t0 * (HW / 4) + gid;
    v2u* rp = (v2u*)Rbuf + gid;
    v4f* st = (v4f*)state;

    v4f p, r;
    if (t0 == 0) {
        p = (v4f)0.f; r = (v4f)0.f;
    } else {
        p = st[gid];
        r = st[HW / 4 + gid];
    }

#define SCAN_STEP(xv)                                                        \
    {                                                                        \
        v2u pk;                                                              \
        pk.x = f2bf_rne(r.x) | (f2bf_rne(r.y) << 16);                        \
        pk.y = f2bf_rne(r.z) | (f2bf_rne(r.w) << 16);                        \
        rp[(size_t)t * (HW / 4)] = pk;                                       \
        v4f rn = DECAY * r + p;                                              \
        p = DECAY * p + (xv);                                                \
        r = rn;                                                              \
        ++t;                                                                 \
    }

    int t = 0;
    const int t4 = tc & ~3;
    for (; t < t4;) {
        v4f x0 = __builtin_nontemporal_load(&xp[(size_t)(t + 0) * (HW / 4)]);
        v4f x1 = __builtin_nontemporal_load(&xp[(size_t)(t + 1) * (HW / 4)]);
        v4f x2 = __builtin_nontemporal_load(&xp[(size_t)(t + 2) * (HW / 4)]);
        v4f x3 = __builtin_nontemporal_load(&xp[(size_t)(t + 3) * (HW / 4)]);
        SCAN_STEP(x0); SCAN_STEP(x1); SCAN_STEP(x2); SCAN_STEP(x3);
    }
    for (; t < tc;) {
        v4f xv = __builtin_nontemporal_load(&xp[(size_t)t * (HW / 4)]);
        SCAN_STEP(xv);
    }
#undef SCAN_STEP

    st[gid] = p;
    st[HW / 4 + gid] = r;
}

// ---------------------------------------------------------------------------
// Pass B: 9x9 conv, zero pad 4, bf16 input / fp32 output.
// Tile 256 wide x 16 tall. Thread: i = tid&63 -> 4-wide col run, j = tid>>6 ->
// 4-tall patch. A wave (64 lanes) = ONE region row per ds_read: conflict-free.
// Register-rotating rows: each thread reads its 12 input rows once, feeding up
// to 4 pending output rows. acc[4][4] + win[12] keeps natural VGPR ~64 ->
// 7-8 waves/SIMD WITHOUT launch_bounds coercion (round-6 lesson: forcing the
// 2nd arg spills to scratch). Weights via uniform loads -> SGPRs.
// ---------------------------------------------------------------------------
#define BX 256
#define BY 16
#define RGROWS 24     // 16 + 8 halo
#define RSTRE 272     // LDS row stride in bf16 elems (544 B)
#define RCHUNK 66     // 4-elem (8 B) chunks per row (264 elems used)

__global__ __launch_bounds__(256) void conv_chunk(
    const unsigned short* __restrict__ Rbuf, const float* __restrict__ wp,
    float* __restrict__ out, int t0)
{
    __shared__ unsigned short reg[RGROWS * RSTRE];   // 13,056 B

    const int tid = threadIdx.x;
    const int tX = blockIdx.x, tY = blockIdx.y, tz = blockIdx.z;
    const int X0 = tX * BX - 4, Y0 = tY * BY - 4;
    const unsigned short* Rp = Rbuf + (size_t)tz * HW;

    float wr[81];                      // wave-uniform -> s_load into SGPRs
    #pragma unroll
    for (int q = 0; q < 81; ++q) wr[q] = wp[q];

    // stage region (bf16, 8B chunks; chunks never straddle the image edge)
    #pragma unroll
    for (int k = 0; k < 7; ++k) {
        int e = tid + k * 256;
        if (e < RGROWS * RCHUNK) {
            int rr = e / RCHUNK, c = e - rr * RCHUNK;
            int gy = Y0 + rr, gx = X0 + 4 * c;
            uint2 v = make_uint2(0u, 0u);
            if ((unsigned)gy < H && (unsigned)gx < W)
                v = *(const uint2*)(Rp + (size_t)(gy * W + gx));
            *(uint2*)(&reg[rr * RSTRE + 4 * c]) = v;
        }
    }
    __syncthreads();

    const int i = tid & 63;     // col chunk: region elems 4i..4i+11 window
    const int j = tid >> 6;     // 0..3 -> output rows 4j..4j+3
    const int rbase = 4 * j;

    float acc[4][4];
    #pragma unroll
    for (int a = 0; a < 4; ++a)
        #pragma unroll
        for (int b = 0; b < 4; ++b) acc[a][b] = 0.f;

    #pragma unroll
    for (int r = 0; r < 12; ++r) {
        const unsigned short* rp = &reg[(rbase + r) * RSTRE + 4 * i];
        uint2 va = *(const uint2*)(rp);      // elems 0..3
        uint2 vb = *(const uint2*)(rp + 4);  // elems 4..7
        uint2 vc = *(const uint2*)(rp + 8);  // elems 8..11
        float win[12];
        win[0] = bf_lo(va.x);  win[1] = bf_hi(va.x);
        win[2] = bf_lo(va.y);  win[3] = bf_hi(va.y);
        win[4] = bf_lo(vb.x);  win[5] = bf_hi(vb.x);
        win[6] = bf_lo(vb.y);  win[7] = bf_hi(vb.y);
        win[8] = bf_lo(vc.x);  win[9] = bf_hi(vc.x);
        win[10] = bf_lo(vc.y); win[11] = bf_hi(vc.y);
        #pragma unroll
        for (int oy = 0; oy < 4; ++oy) {
            const int ky = r - oy;                 // compile-time after unroll
            if (ky >= 0 && ky <= 8) {
                #pragma unroll
                for (int kx = 0; kx < 9; ++kx) {
                    float wv = wr[ky * 9 + kx];
                    acc[oy][0] = __builtin_fmaf(wv, win[kx + 0], acc[oy][0]);
                    acc[oy][1] = __builtin_fmaf(wv, win[kx + 1], acc[oy][1]);
                    acc[oy][2] = __builtin_fmaf(wv, win[kx + 2], acc[oy][2]);
                    acc[oy][3] = __builtin_fmaf(wv, win[kx + 3], acc[oy][3]);
                }
            }
        }
    }

    float* op = out + (size_t)(t0 + tz) * HW
                    + (size_t)((tY * BY + 4 * j) * W) + (tX * BX + 4 * i);
    #pragma unroll
    for (int oy = 0; oy < 4; ++oy) {
        v4f v = {acc[oy][0], acc[oy][1], acc[oy][2], acc[oy][3]};
        __builtin_nontemporal_store(v, (v4f*)(op + (size_t)oy * W));
    }
}

// ---------------------------------------------------------------------------
extern "C" void kernel_launch(void* const* d_in, const int* in_sizes, int n_in,
                              void* d_out, int out_size, void* d_ws, size_t ws_size,
                              hipStream_t stream) {
    const float* x = (const float*)d_in[0];  // [128,1,512,512]
    const float* w = (const float*)d_in[1];  // [1,1,9,9]
    float* out = (float*)d_out;              // [128,1,512,512]

    float* state = (float*)d_ws;                               // 2 fp32 planes
    unsigned short* Rbuf = (unsigned short*)(state + 2 * (size_t)HW);

    size_t state_b = 2 * (size_t)HW * sizeof(float);
    size_t plane_b = (size_t)HW * sizeof(unsigned short);
    int maxTc = 1;
    if (ws_size > state_b + plane_b)
        maxTc = (int)((ws_size - state_b) / plane_b);
    int Tc = T;
    if (Tc > maxTc) Tc = maxTc;
    if (Tc < 1) Tc = 1;

    for (int t0 = 0; t0 < T; t0 += Tc) {
        int tc = T - t0;
        if (tc > Tc) tc = Tc;
        scan_chunk<<<dim3(HW / 1024), 256, 0, stream>>>(
            x, (unsigned int*)Rbuf, state, t0, tc);
        conv_chunk<<<dim3(W / BX, H / BY, tc), 256, 0, stream>>>(
            Rbuf, w, out, t0);
    }
}

// Round 9
// 117.547 us; speedup vs baseline: 12.0805x; 1.0137x over previous
//
#include <hip/hip_runtime.h>

#define H 512
#define W 512
#define HW (H * W)
#define T 128
#define DECAY 0.8f

typedef float v4f __attribute__((ext_vector_type(4)));
typedef unsigned int v2u __attribute__((ext_vector_type(2)));
typedef _Float16 h2 __attribute__((ext_vector_type(2)));
typedef __fp16 hr2 __attribute__((ext_vector_type(2)));   // cvt_pkrtz native type

__device__ __forceinline__ float dot2(unsigned int a, unsigned int b, float c) {
    return __builtin_amdgcn_fdot2(__builtin_bit_cast(h2, a),
                                  __builtin_bit_cast(h2, b), c, false);
}

// ---------------------------------------------------------------------------
// Pack conv weights into f16 pairs (one wave, once):
//   wq[ky*6+0..3] = {w0,w1}{w2,w3}{w4,w5}{w6,w7}   wq[ky*6+4] = {w8,0}
//   wq[ky*6+5]    = {0,w8}
// ---------------------------------------------------------------------------
__global__ void pack_w(const float* __restrict__ wp, unsigned int* __restrict__ wq)
{
    int ky = threadIdx.x;
    if (ky < 9) {
        unsigned int hh[9];
        for (int kx = 0; kx < 9; ++kx) {
            _Float16 hv = (_Float16)wp[ky * 9 + kx];
            hh[kx] = (unsigned int)__builtin_bit_cast(unsigned short, hv);
        }
        wq[ky * 6 + 0] = hh[0] | (hh[1] << 16);
        wq[ky * 6 + 1] = hh[2] | (hh[3] << 16);
        wq[ky * 6 + 2] = hh[4] | (hh[5] << 16);
        wq[ky * 6 + 3] = hh[6] | (hh[7] << 16);
        wq[ky * 6 + 4] = hh[8];
        wq[ky * 6 + 5] = hh[8] << 16;
    }
}

// ---------------------------------------------------------------------------
// Pass A: pointwise double-EMA scan. float4 lanes, 4-step load batching.
// R stored as packed f16 (more mantissa than bf16 -> better accuracy).
//   p' = .8p + x[t];  r' = .8r + p_old;  Rbuf[t] = r entering step t.
// ---------------------------------------------------------------------------
__global__ __launch_bounds__(256) void scan_chunk(
    const float* __restrict__ x, unsigned int* __restrict__ Rbuf,
    float* __restrict__ state, int t0, int tc)
{
    const int gid = blockIdx.x * 256 + threadIdx.x;      // 0 .. HW/4-1
    const v4f* xp = (const v4f*)x + (size_t)t0 * (HW / 4) + gid;
    v2u* rp = (v2u*)Rbuf + gid;
    v4f* st = (v4f*)state;

    v4f p, r;
    if (t0 == 0) {
        p = (v4f)0.f; r = (v4f)0.f;
    } else {
        p = st[gid];
        r = st[HW / 4 + gid];
    }

#define SCAN_STEP(xv)                                                        \
    {                                                                        \
        hr2 h0 = __builtin_amdgcn_cvt_pkrtz(r.x, r.y);                       \
        hr2 h1 = __builtin_amdgcn_cvt_pkrtz(r.z, r.w);                       \
        v2u pk;                                                              \
        pk.x = __builtin_bit_cast(unsigned int, h0);                         \
        pk.y = __builtin_bit_cast(unsigned int, h1);                         \
        rp[(size_t)t * (HW / 4)] = pk;                                       \
        v4f rn = DECAY * r + p;                                              \
        p = DECAY * p + (xv);                                                \
        r = rn;                                                              \
        ++t;                                                                 \
    }

    int t = 0;
    const int t4 = tc & ~3;
    for (; t < t4;) {
        v4f x0 = __builtin_nontemporal_load(&xp[(size_t)(t + 0) * (HW / 4)]);
        v4f x1 = __builtin_nontemporal_load(&xp[(size_t)(t + 1) * (HW / 4)]);
        v4f x2 = __builtin_nontemporal_load(&xp[(size_t)(t + 2) * (HW / 4)]);
        v4f x3 = __builtin_nontemporal_load(&xp[(size_t)(t + 3) * (HW / 4)]);
        SCAN_STEP(x0); SCAN_STEP(x1); SCAN_STEP(x2); SCAN_STEP(x3);
    }
    for (; t < tc;) {
        v4f xv = __builtin_nontemporal_load(&xp[(size_t)t * (HW / 4)]);
        SCAN_STEP(xv);
    }
#undef SCAN_STEP

    st[gid] = p;
    st[HW / 4 + gid] = r;
}

// ---------------------------------------------------------------------------
// Pass B: 9x9 conv, zero pad 4, f16 input / fp32 output, v_dot2_f32_f16.
// Tile 256x16. Thread: i = tid&63 -> 4 cols, j = tid>>6 -> 4 rows. Wave = one
// region row per ds_read: conflict-free. Per row: 3 ds_read_b64 (pairs
// e0..e5), 5 alignbit (shifted pairs o0..o4), 20 dot2 -> 2 MACs/instr.
// Weights pre-packed, loaded uniform -> SGPRs. No launch_bounds coercion.
// ---------------------------------------------------------------------------
#define BX 256
#define BY 16
#define RGROWS 24     // 16 + 8 halo
#define RSTRE 272     // LDS row stride in f16 elems (544 B)
#define RCHUNK 66     // 4-elem (8 B) chunks per row (264 elems used)

__global__ __launch_bounds__(256) void conv_chunk(
    const unsigned short* __restrict__ Rbuf, const unsigned int* __restrict__ wq,
    float* __restrict__ out, int t0)
{
    __shared__ unsigned short reg[RGROWS * RSTRE];   // 13,056 B

    const int tid = threadIdx.x;
    const int tX = blockIdx.x, tY = blockIdx.y, tz = blockIdx.z;
    const int X0 = tX * BX - 4, Y0 = tY * BY - 4;
    const unsigned short* Rp = Rbuf + (size_t)tz * HW;

    unsigned int wk[54];               // uniform -> s_load into SGPRs
    #pragma unroll
    for (int q = 0; q < 54; ++q) wk[q] = wq[q];

    // stage region (f16, 8B chunks; chunks never straddle the image edge)
    #pragma unroll
    for (int k = 0; k < 7; ++k) {
        int e = tid + k * 256;
        if (e < RGROWS * RCHUNK) {
            int rr = e / RCHUNK, c = e - rr * RCHUNK;
            int gy = Y0 + rr, gx = X0 + 4 * c;
            uint2 v = make_uint2(0u, 0u);
            if ((unsigned)gy < H && (unsigned)gx < W)
                v = *(const uint2*)(Rp + (size_t)(gy * W + gx));
            *(uint2*)(&reg[rr * RSTRE + 4 * c]) = v;
        }
    }
    __syncthreads();

    const int i = tid & 63;     // col chunk: region elems 4i..4i+11 window
    const int j = tid >> 6;     // 0..3 -> output rows 4j..4j+3
    const int rbase = 4 * j;

    float acc[4][4];
    #pragma unroll
    for (int a = 0; a < 4; ++a)
        #pragma unroll
        for (int b = 0; b < 4; ++b) acc[a][b] = 0.f;

    #pragma unroll
    for (int r = 0; r < 12; ++r) {
        const unsigned short* rp = &reg[(rbase + r) * RSTRE + 4 * i];
        uint2 va = *(const uint2*)(rp);      // e0 e1  (elems 0..3)
        uint2 vb = *(const uint2*)(rp + 4);  // e2 e3  (elems 4..7)
        uint2 vc = *(const uint2*)(rp + 8);  // e4 e5  (elems 8..11)
        unsigned int e0 = va.x, e1 = va.y, e2 = vb.x;
        unsigned int e3 = vb.y, e4 = vc.x, e5 = vc.y;
        unsigned int o0 = __builtin_amdgcn_alignbit(e1, e0, 16); // {1,2}
        unsigned int o1 = __builtin_amdgcn_alignbit(e2, e1, 16); // {3,4}
        unsigned int o2 = __builtin_amdgcn_alignbit(e3, e2, 16); // {5,6}
        unsigned int o3 = __builtin_amdgcn_alignbit(e4, e3, 16); // {7,8}
        unsigned int o4 = __builtin_amdgcn_alignbit(e5, e4, 16); // {9,10}
        #pragma unroll
        for (int oy = 0; oy < 4; ++oy) {
            const int ky = r - oy;                 // compile-time after unroll
            if (ky >= 0 && ky <= 8) {
                const unsigned int* wc = &wk[ky * 6];
                acc[oy][0] = dot2(e0, wc[0], acc[oy][0]);
                acc[oy][0] = dot2(e1, wc[1], acc[oy][0]);
                acc[oy][0] = dot2(e2, wc[2], acc[oy][0]);
                acc[oy][0] = dot2(e3, wc[3], acc[oy][0]);
                acc[oy][0] = dot2(e4, wc[4], acc[oy][0]);
                acc[oy][1] = dot2(o0, wc[0], acc[oy][1]);
                acc[oy][1] = dot2(o1, wc[1], acc[oy][1]);
                acc[oy][1] = dot2(o2, wc[2], acc[oy][1]);
                acc[oy][1] = dot2(o3, wc[3], acc[oy][1]);
                acc[oy][1] = dot2(o4, wc[4], acc[oy][1]);
                acc[oy][2] = dot2(e1, wc[0], acc[oy][2]);
                acc[oy][2] = dot2(e2, wc[1], acc[oy][2]);
                acc[oy][2] = dot2(e3, wc[2], acc[oy][2]);
                acc[oy][2] = dot2(e4, wc[3], acc[oy][2]);
                acc[oy][2] = dot2(e5, wc[4], acc[oy][2]);
                acc[oy][3] = dot2(o1, wc[0], acc[oy][3]);
                acc[oy][3] = dot2(o2, wc[1], acc[oy][3]);
                acc[oy][3] = dot2(o3, wc[2], acc[oy][3]);
                acc[oy][3] = dot2(o4, wc[3], acc[oy][3]);
                acc[oy][3] = dot2(e5, wc[5], acc[oy][3]);
            }
        }
    }

    float* op = out + (size_t)(t0 + tz) * HW
                    + (size_t)((tY * BY + 4 * j) * W) + (tX * BX + 4 * i);
    #pragma unroll
    for (int oy = 0; oy < 4; ++oy) {
        v4f v = {acc[oy][0], acc[oy][1], acc[oy][2], acc[oy][3]};
        __builtin_nontemporal_store(v, (v4f*)(op + (size_t)oy * W));
    }
}

// ---------------------------------------------------------------------------
extern "C" void kernel_launch(void* const* d_in, const int* in_sizes, int n_in,
                              void* d_out, int out_size, void* d_ws, size_t ws_size,
                              hipStream_t stream) {
    const float* x = (const float*)d_in[0];  // [128,1,512,512]
    const float* w = (const float*)d_in[1];  // [1,1,9,9]
    float* out = (float*)d_out;              // [128,1,512,512]

    unsigned int* wq = (unsigned int*)d_ws;                    // 64 u32 slot
    float* state = (float*)((char*)d_ws + 256);                // 2 fp32 planes
    unsigned short* Rbuf = (unsigned short*)(state + 2 * (size_t)HW);

    size_t head_b = 256 + 2 * (size_t)HW * sizeof(float);
    size_t plane_b = (size_t)HW * sizeof(unsigned short);
    int maxTc = 1;
    if (ws_size > head_b + plane_b)
        maxTc = (int)((ws_size - head_b) / plane_b);
    int Tc = T;
    if (Tc > maxTc) Tc = maxTc;
    if (Tc < 1) Tc = 1;

    pack_w<<<1, 64, 0, stream>>>(w, wq);

    for (int t0 = 0; t0 < T; t0 += Tc) {
        int tc = T - t0;
        if (tc > Tc) tc = Tc;
        scan_chunk<<<dim3(HW / 1024), 256, 0, stream>>>(
            x, (unsigned int*)Rbuf, state, t0, tc);
        conv_chunk<<<dim3(W / BX, H / BY, tc), 256, 0, stream>>>(
            Rbuf, wq, out, t0);
    }
}

// Round 10
// 100.859 us; speedup vs baseline: 14.0793x; 1.1655x over previous
//
#include <hip/hip_runtime.h>

#define H 512
#define W 512
#define HW (H * W)
#define T 128
#define DECAY 0.8f

typedef float v4f __attribute__((ext_vector_type(4)));
typedef unsigned int v2u __attribute__((ext_vector_type(2)));
typedef _Float16 h2 __attribute__((ext_vector_type(2)));
typedef __fp16 hr2 __attribute__((ext_vector_type(2)));   // cvt_pkrtz native type

__device__ __forceinline__ float dot2(unsigned int a, unsigned int b, float c) {
    return __builtin_amdgcn_fdot2(__builtin_bit_cast(h2, a),
                                  __builtin_bit_cast(h2, b), c, false);
}

// ---------------------------------------------------------------------------
// Pack conv weights into f16 pairs (one wave, once).
// ---------------------------------------------------------------------------
__global__ void pack_w(const float* __restrict__ wp, unsigned int* __restrict__ wq)
{
    int ky = threadIdx.x;
    if (ky < 9) {
        unsigned int hh[9];
        for (int kx = 0; kx < 9; ++kx) {
            _Float16 hv = (_Float16)wp[ky * 9 + kx];
            hh[kx] = (unsigned int)__builtin_bit_cast(unsigned short, hv);
        }
        wq[ky * 6 + 0] = hh[0] | (hh[1] << 16);
        wq[ky * 6 + 1] = hh[2] | (hh[3] << 16);
        wq[ky * 6 + 2] = hh[4] | (hh[5] << 16);
        wq[ky * 6 + 3] = hh[6] | (hh[7] << 16);
        wq[ky * 6 + 4] = hh[8];
        wq[ky * 6 + 5] = hh[8] << 16;
    }
}

// ---------------------------------------------------------------------------
// Pass A: pointwise double-EMA scan (unchanged, ~33 us, ~6.1 TB/s).
// ---------------------------------------------------------------------------
__global__ __launch_bounds__(256) void scan_chunk(
    const float* __restrict__ x, unsigned int* __restrict__ Rbuf,
    float* __restrict__ state, int t0, int tc)
{
    const int gid = blockIdx.x * 256 + threadIdx.x;      // 0 .. HW/4-1
    const v4f* xp = (const v4f*)x + (size_t)t0 * (HW / 4) + gid;
    v2u* rp = (v2u*)Rbuf + gid;
    v4f* st = (v4f*)state;

    v4f p, r;
    if (t0 == 0) {
        p = (v4f)0.f; r = (v4f)0.f;
    } else {
        p = st[gid];
        r = st[HW / 4 + gid];
    }

#define SCAN_STEP(xv)                                                        \
    {                                                                        \
        hr2 h0 = __builtin_amdgcn_cvt_pkrtz(r.x, r.y);                       \
        hr2 h1 = __builtin_amdgcn_cvt_pkrtz(r.z, r.w);                       \
        v2u pk;                                                              \
        pk.x = __builtin_bit_cast(unsigned int, h0);                         \
        pk.y = __builtin_bit_cast(unsigned int, h1);                         \
        rp[(size_t)t * (HW / 4)] = pk;                                       \
        v4f rn = DECAY * r + p;                                              \
        p = DECAY * p + (xv);                                                \
        r = rn;                                                              \
        ++t;                                                                 \
    }

    int t = 0;
    const int t4 = tc & ~3;
    for (; t < t4;) {
        v4f x0 = __builtin_nontemporal_load(&xp[(size_t)(t + 0) * (HW / 4)]);
        v4f x1 = __builtin_nontemporal_load(&xp[(size_t)(t + 1) * (HW / 4)]);
        v4f x2 = __builtin_nontemporal_load(&xp[(size_t)(t + 2) * (HW / 4)]);
        v4f x3 = __builtin_nontemporal_load(&xp[(size_t)(t + 3) * (HW / 4)]);
        SCAN_STEP(x0); SCAN_STEP(x1); SCAN_STEP(x2); SCAN_STEP(x3);
    }
    for (; t < tc;) {
        v4f xv = __builtin_nontemporal_load(&xp[(size_t)t * (HW / 4)]);
        SCAN_STEP(xv);
    }
#undef SCAN_STEP

    st[gid] = p;
    st[HW / 4 + gid] = r;
}

// ---------------------------------------------------------------------------
// Pass B: 9x9 conv, f16 in / fp32 out, v_dot2_f32_f16, SOFTWARE-PIPELINED
// over 8 time planes per block (same spatial tile). Double-buffered LDS:
// per plane z -> issue global loads for z+1 into regs, compute z from buf,
// ds_write z+1 into other buf, ONE barrier. Loads stay continuously in
// flight -> streaming instead of stage/compute pulses (round-9 lesson).
// ---------------------------------------------------------------------------
#define BX 256
#define BY 16
#define ZP 8          // time planes per block
#define RGROWS 24     // 16 + 8 halo
#define RSTRE 272     // LDS row stride in f16 elems (544 B)
#define RCHUNK 66     // 4-elem (8 B) chunks per row (264 elems used)
#define NCHK 7        // ceil(24*66/256)

__global__ __launch_bounds__(256) void conv_chunk(
    const unsigned short* __restrict__ Rbuf, const unsigned int* __restrict__ wq,
    float* __restrict__ out, int t0, int tc)
{
    __shared__ unsigned short regA[RGROWS * RSTRE];   // 13,056 B
    __shared__ unsigned short regB[RGROWS * RSTRE];

    const int tid = threadIdx.x;
    const int tX = blockIdx.x, tY = blockIdx.y;
    const int z0 = blockIdx.z * ZP;
    const int zc = (tc - z0 < ZP) ? (tc - z0) : ZP;
    const int X0 = tX * BX - 4, Y0 = tY * BY - 4;
    const unsigned short* Rbase = Rbuf + (size_t)z0 * HW;

    unsigned int wk[54];               // uniform -> SGPRs
    #pragma unroll
    for (int q = 0; q < 54; ++q) wk[q] = wq[q];

    // per-thread staging slots (static for whole kernel)
    int goffk[NCHK], laddrk[NCHK];
    unsigned smask = 0;
    #pragma unroll
    for (int k = 0; k < NCHK; ++k) {
        int e = tid + 256 * k;
        int rr = e / RCHUNK, c = e - rr * RCHUNK;
        int gy = Y0 + rr, gx = X0 + 4 * c;
        bool inr = (e < RGROWS * RCHUNK);
        bool inimg = inr && (unsigned)gy < H && (unsigned)gx < W;
        goffk[k] = gy * W + gx;
        laddrk[k] = rr * RSTRE + 4 * c;
        if (inr) smask |= (1u << k);
        if (inimg) smask |= (1u << (k + 16));
    }

#define LOADPLANE(pf, zz)                                                    \
    {                                                                        \
        const unsigned short* Rp_ = Rbase + (size_t)(zz) * HW;               \
        _Pragma("unroll")                                                    \
        for (int k = 0; k < NCHK; ++k)                                       \
            pf[k] = (smask >> (k + 16) & 1)                                  \
                        ? *(const uint2*)(Rp_ + goffk[k])                    \
                        : make_uint2(0u, 0u);                                \
    }

#define WRITEPLANE(buf, pf)                                                  \
    {                                                                        \
        _Pragma("unroll")                                                    \
        for (int k = 0; k < NCHK; ++k)                                       \
            if (smask >> k & 1)                                              \
                *(uint2*)(&buf[laddrk[k]]) = pf[k];                          \
    }

    const int i = tid & 63;     // col chunk: region elems 4i..4i+11 window
    const int j = tid >> 6;     // 0..3 -> output rows 4j..4j+3
    const int rbase = 4 * j;
    float* opb = out + (size_t)(t0 + z0) * HW
                     + (size_t)((tY * BY + 4 * j) * W) + (tX * BX + 4 * i);

    uint2 pf[NCHK];
    LOADPLANE(pf, 0);
    WRITEPLANE(regA, pf);
    __syncthreads();

    for (int zz = 0; zz < zc; ++zz) {
        if (zz + 1 < zc) LOADPLANE(pf, zz + 1);

        const unsigned short* bufc = (zz & 1) ? regB : regA;
        unsigned short* bufn = (zz & 1) ? regA : regB;

        float acc[4][4];
        #pragma unroll
        for (int a = 0; a < 4; ++a)
            #pragma unroll
            for (int b = 0; b < 4; ++b) acc[a][b] = 0.f;

        #pragma unroll
        for (int r = 0; r < 12; ++r) {
            const unsigned short* rp = &bufc[(rbase + r) * RSTRE + 4 * i];
            uint2 va = *(const uint2*)(rp);
            uint2 vb = *(const uint2*)(rp + 4);
            uint2 vc = *(const uint2*)(rp + 8);
            unsigned int e0 = va.x, e1 = va.y, e2 = vb.x;
            unsigned int e3 = vb.y, e4 = vc.x, e5 = vc.y;
            unsigned int o0 = __builtin_amdgcn_alignbit(e1, e0, 16);
            unsigned int o1 = __builtin_amdgcn_alignbit(e2, e1, 16);
            unsigned int o2 = __builtin_amdgcn_alignbit(e3, e2, 16);
            unsigned int o3 = __builtin_amdgcn_alignbit(e4, e3, 16);
            unsigned int o4 = __builtin_amdgcn_alignbit(e5, e4, 16);
            #pragma unroll
            for (int oy = 0; oy < 4; ++oy) {
                const int ky = r - oy;             // compile-time after unroll
                if (ky >= 0 && ky <= 8) {
                    const unsigned int* wc = &wk[ky * 6];
                    acc[oy][0] = dot2(e0, wc[0], acc[oy][0]);
                    acc[oy][0] = dot2(e1, wc[1], acc[oy][0]);
                    acc[oy][0] = dot2(e2, wc[2], acc[oy][0]);
                    acc[oy][0] = dot2(e3, wc[3], acc[oy][0]);
                    acc[oy][0] = dot2(e4, wc[4], acc[oy][0]);
                    acc[oy][1] = dot2(o0, wc[0], acc[oy][1]);
                    acc[oy][1] = dot2(o1, wc[1], acc[oy][1]);
                    acc[oy][1] = dot2(o2, wc[2], acc[oy][1]);
                    acc[oy][1] = dot2(o3, wc[3], acc[oy][1]);
                    acc[oy][1] = dot2(o4, wc[4], acc[oy][1]);
                    acc[oy][2] = dot2(e1, wc[0], acc[oy][2]);
                    acc[oy][2] = dot2(e2, wc[1], acc[oy][2]);
                    acc[oy][2] = dot2(e3, wc[2], acc[oy][2]);
                    acc[oy][2] = dot2(e4, wc[3], acc[oy][2]);
                    acc[oy][2] = dot2(e5, wc[4], acc[oy][2]);
                    acc[oy][3] = dot2(o1, wc[0], acc[oy][3]);
                    acc[oy][3] = dot2(o2, wc[1], acc[oy][3]);
                    acc[oy][3] = dot2(o3, wc[2], acc[oy][3]);
                    acc[oy][3] = dot2(o4, wc[3], acc[oy][3]);
                    acc[oy][3] = dot2(e5, wc[5], acc[oy][3]);
                }
            }
        }

        float* op = opb + (size_t)zz * HW;
        #pragma unroll
        for (int oy = 0; oy < 4; ++oy) {
            v4f v = {acc[oy][0], acc[oy][1], acc[oy][2], acc[oy][3]};
            __builtin_nontemporal_store(v, (v4f*)(op + (size_t)oy * W));
        }

        if (zz + 1 < zc) WRITEPLANE(bufn, pf);
        __syncthreads();
    }
#undef LOADPLANE
#undef WRITEPLANE
}

// ---------------------------------------------------------------------------
extern "C" void kernel_launch(void* const* d_in, const int* in_sizes, int n_in,
                              void* d_out, int out_size, void* d_ws, size_t ws_size,
                              hipStream_t stream) {
    const float* x = (const float*)d_in[0];  // [128,1,512,512]
    const float* w = (const float*)d_in[1];  // [1,1,9,9]
    float* out = (float*)d_out;              // [128,1,512,512]

    unsigned int* wq = (unsigned int*)d_ws;                    // 64 u32 slot
    float* state = (float*)((char*)d_ws + 256);                // 2 fp32 planes
    unsigned short* Rbuf = (unsigned short*)(state + 2 * (size_t)HW);

    size_t head_b = 256 + 2 * (size_t)HW * sizeof(float);
    size_t plane_b = (size_t)HW * sizeof(unsigned short);
    int maxTc = 1;
    if (ws_size > head_b + plane_b)
        maxTc = (int)((ws_size - head_b) / plane_b);
    int Tc = T;
    if (Tc > maxTc) Tc = maxTc;
    if (Tc < 1) Tc = 1;

    pack_w<<<1, 64, 0, stream>>>(w, wq);

    for (int t0 = 0; t0 < T; t0 += Tc) {
        int tc = T - t0;
        if (tc > Tc) tc = Tc;
        scan_chunk<<<dim3(HW / 1024), 256, 0, stream>>>(
            x, (unsigned int*)Rbuf, state, t0, tc);
        conv_chunk<<<dim3(W / BX, H / BY, (tc + ZP - 1) / ZP), 256, 0, stream>>>(
            Rbuf, wq, out, t0, tc);
    }
}

// Round 11
// 97.592 us; speedup vs baseline: 14.5506x; 1.0335x over previous
//
#include <hip/hip_runtime.h>

#define H 512
#define W 512
#define HW (H * W)
#define T 128
#define DECAY 0.8f

typedef float v4f __attribute__((ext_vector_type(4)));
typedef unsigned int v2u __attribute__((ext_vector_type(2)));
typedef _Float16 h2 __attribute__((ext_vector_type(2)));
typedef __fp16 hr2 __attribute__((ext_vector_type(2)));   // cvt_pkrtz native type

__device__ __forceinline__ float dot2(unsigned int a, unsigned int b, float c) {
    return __builtin_amdgcn_fdot2(__builtin_bit_cast(h2, a),
                                  __builtin_bit_cast(h2, b), c, false);
}

// ---------------------------------------------------------------------------
// Pass A: pointwise double-EMA scan (~33 us, ~6.1 TB/s). Block 0 also packs
// the conv weights into f16 pairs (saves a separate launch).
// ---------------------------------------------------------------------------
__global__ __launch_bounds__(256) void scan_chunk(
    const float* __restrict__ x, unsigned int* __restrict__ Rbuf,
    float* __restrict__ state, const float* __restrict__ wp,
    unsigned int* __restrict__ wq, int t0, int tc)
{
    if (t0 == 0 && blockIdx.x == 0 && threadIdx.x < 9) {
        int ky = threadIdx.x;
        unsigned int hh[9];
        #pragma unroll
        for (int kx = 0; kx < 9; ++kx) {
            _Float16 hv = (_Float16)wp[ky * 9 + kx];
            hh[kx] = (unsigned int)__builtin_bit_cast(unsigned short, hv);
        }
        wq[ky * 6 + 0] = hh[0] | (hh[1] << 16);
        wq[ky * 6 + 1] = hh[2] | (hh[3] << 16);
        wq[ky * 6 + 2] = hh[4] | (hh[5] << 16);
        wq[ky * 6 + 3] = hh[6] | (hh[7] << 16);
        wq[ky * 6 + 4] = hh[8];
        wq[ky * 6 + 5] = hh[8] << 16;
    }

    const int gid = blockIdx.x * 256 + threadIdx.x;      // 0 .. HW/4-1
    const v4f* xp = (const v4f*)x + (size_t)t0 * (HW / 4) + gid;
    v2u* rp = (v2u*)Rbuf + gid;
    v4f* st = (v4f*)state;

    v4f p, r;
    if (t0 == 0) {
        p = (v4f)0.f; r = (v4f)0.f;
    } else {
        p = st[gid];
        r = st[HW / 4 + gid];
    }

#define SCAN_STEP(xv)                                                        \
    {                                                                        \
        hr2 h0 = __builtin_amdgcn_cvt_pkrtz(r.x, r.y);                       \
        hr2 h1 = __builtin_amdgcn_cvt_pkrtz(r.z, r.w);                       \
        v2u pk;                                                              \
        pk.x = __builtin_bit_cast(unsigned int, h0);                         \
        pk.y = __builtin_bit_cast(unsigned int, h1);                         \
        rp[(size_t)t * (HW / 4)] = pk;                                       \
        v4f rn = DECAY * r + p;                                              \
        p = DECAY * p + (xv);                                                \
        r = rn;                                                              \
        ++t;                                                                 \
    }

    int t = 0;
    const int t4 = tc & ~3;
    for (; t < t4;) {
        v4f x0 = __builtin_nontemporal_load(&xp[(size_t)(t + 0) * (HW / 4)]);
        v4f x1 = __builtin_nontemporal_load(&xp[(size_t)(t + 1) * (HW / 4)]);
        v4f x2 = __builtin_nontemporal_load(&xp[(size_t)(t + 2) * (HW / 4)]);
        v4f x3 = __builtin_nontemporal_load(&xp[(size_t)(t + 3) * (HW / 4)]);
        SCAN_STEP(x0); SCAN_STEP(x1); SCAN_STEP(x2); SCAN_STEP(x3);
    }
    for (; t < tc;) {
        v4f xv = __builtin_nontemporal_load(&xp[(size_t)t * (HW / 4)]);
        SCAN_STEP(xv);
    }
#undef SCAN_STEP

    st[gid] = p;
    st[HW / 4 + gid] = r;
}

// ---------------------------------------------------------------------------
// Pass B: 9x9 conv, f16 in / fp32 out, v_dot2_f32_f16, 8 planes per block,
// TWO-PLANE-DEEP register prefetch (pfA/pfB): each plane's loads are issued
// two compute-phases before their ds_write (~1200 cyc cover vs ~900 cyc HBM
// latency). Double-buffered LDS, one barrier per plane. Wave = one region
// row per ds_read: conflict-free.
// ---------------------------------------------------------------------------
#define BX 256
#define BY 16
#define ZP 8          // time planes per block
#define RGROWS 24     // 16 + 8 halo
#define RSTRE 272     // LDS row stride in f16 elems (544 B)
#define RCHUNK 66     // 4-elem (8 B) chunks per row (264 elems used)
#define NCHK 7        // ceil(24*66/256)

__global__ __launch_bounds__(256) void conv_chunk(
    const unsigned short* __restrict__ Rbuf, const unsigned int* __restrict__ wq,
    float* __restrict__ out, int t0, int tc)
{
    __shared__ unsigned short regA[RGROWS * RSTRE];   // 13,056 B
    __shared__ unsigned short regB[RGROWS * RSTRE];

    const int tid = threadIdx.x;
    const int tX = blockIdx.x, tY = blockIdx.y;
    const int z0 = blockIdx.z * ZP;
    const int zc = (tc - z0 < ZP) ? (tc - z0) : ZP;
    const int X0 = tX * BX - 4, Y0 = tY * BY - 4;
    const unsigned short* Rbase = Rbuf + (size_t)z0 * HW;

    unsigned int wk[54];               // uniform -> SGPRs
    #pragma unroll
    for (int q = 0; q < 54; ++q) wk[q] = wq[q];

    // per-thread staging slots (static for whole kernel)
    int goffk[NCHK], laddrk[NCHK];
    unsigned smask = 0;
    #pragma unroll
    for (int k = 0; k < NCHK; ++k) {
        int e = tid + 256 * k;
        int rr = e / RCHUNK, c = e - rr * RCHUNK;
        int gy = Y0 + rr, gx = X0 + 4 * c;
        bool inr = (e < RGROWS * RCHUNK);
        bool inimg = inr && (unsigned)gy < H && (unsigned)gx < W;
        goffk[k] = gy * W + gx;
        laddrk[k] = rr * RSTRE + 4 * c;
        if (inr) smask |= (1u << k);
        if (inimg) smask |= (1u << (k + 16));
    }

#define LOADPLANE(pf, zz)                                                    \
    {                                                                        \
        const unsigned short* Rp_ = Rbase + (size_t)(zz) * HW;               \
        _Pragma("unroll")                                                    \
        for (int k = 0; k < NCHK; ++k)                                       \
            pf[k] = (smask >> (k + 16) & 1)                                  \
                        ? *(const uint2*)(Rp_ + goffk[k])                    \
                        : make_uint2(0u, 0u);                                \
    }

#define WRITEPLANE(buf, pf)                                                  \
    {                                                                        \
        _Pragma("unroll")                                                    \
        for (int k = 0; k < NCHK; ++k)                                       \
            if (smask >> k & 1)                                              \
                *(uint2*)(&buf[laddrk[k]]) = pf[k];                          \
    }

    const int i = tid & 63;     // col chunk: region elems 4i..4i+11 window
    const int j = tid >> 6;     // 0..3 -> output rows 4j..4j+3
    const int rbase = 4 * j;
    float* opb = out + (size_t)(t0 + z0) * HW
                     + (size_t)((tY * BY + 4 * j) * W) + (tX * BX + 4 * i);

#define COMPUTE(bufc, zz)                                                    \
    {                                                                        \
        float acc[4][4];                                                     \
        _Pragma("unroll")                                                    \
        for (int a = 0; a < 4; ++a)                                          \
            _Pragma("unroll")                                                \
            for (int b = 0; b < 4; ++b) acc[a][b] = 0.f;                     \
        _Pragma("unroll")                                                    \
        for (int r = 0; r < 12; ++r) {                                       \
            const unsigned short* rp = &bufc[(rbase + r) * RSTRE + 4 * i];   \
            uint2 va = *(const uint2*)(rp);                                  \
            uint2 vb = *(const uint2*)(rp + 4);                              \
            uint2 vc = *(const uint2*)(rp + 8);                              \
            unsigned int e0 = va.x, e1 = va.y, e2 = vb.x;                    \
            unsigned int e3 = vb.y, e4 = vc.x, e5 = vc.y;                    \
            unsigned int o0 = __builtin_amdgcn_alignbit(e1, e0, 16);         \
            unsigned int o1 = __builtin_amdgcn_alignbit(e2, e1, 16);         \
            unsigned int o2 = __builtin_amdgcn_alignbit(e3, e2, 16);         \
            unsigned int o3 = __builtin_amdgcn_alignbit(e4, e3, 16);         \
            unsigned int o4 = __builtin_amdgcn_alignbit(e5, e4, 16);         \
            _Pragma("unroll")                                                \
            for (int oy = 0; oy < 4; ++oy) {                                 \
                const int ky = r - oy;                                       \
                if (ky >= 0 && ky <= 8) {                                    \
                    const unsigned int* wc = &wk[ky * 6];                    \
                    acc[oy][0] = dot2(e0, wc[0], acc[oy][0]);                \
                    acc[oy][0] = dot2(e1, wc[1], acc[oy][0]);                \
                    acc[oy][0] = dot2(e2, wc[2], acc[oy][0]);                \
                    acc[oy][0] = dot2(e3, wc[3], acc[oy][0]);                \
                    acc[oy][0] = dot2(e4, wc[4], acc[oy][0]);                \
                    acc[oy][1] = dot2(o0, wc[0], acc[oy][1]);                \
                    acc[oy][1] = dot2(o1, wc[1], acc[oy][1]);                \
                    acc[oy][1] = dot2(o2, wc[2], acc[oy][1]);                \
                    acc[oy][1] = dot2(o3, wc[3], acc[oy][1]);                \
                    acc[oy][1] = dot2(o4, wc[4], acc[oy][1]);                \
                    acc[oy][2] = dot2(e1, wc[0], acc[oy][2]);                \
                    acc[oy][2] = dot2(e2, wc[1], acc[oy][2]);                \
                    acc[oy][2] = dot2(e3, wc[2], acc[oy][2]);                \
                    acc[oy][2] = dot2(e4, wc[3], acc[oy][2]);                \
                    acc[oy][2] = dot2(e5, wc[4], acc[oy][2]);                \
                    acc[oy][3] = dot2(o1, wc[0], acc[oy][3]);                \
                    acc[oy][3] = dot2(o2, wc[1], acc[oy][3]);                \
                    acc[oy][3] = dot2(o3, wc[2], acc[oy][3]);                \
                    acc[oy][3] = dot2(o4, wc[3], acc[oy][3]);                \
                    acc[oy][3] = dot2(e5, wc[5], acc[oy][3]);                \
                }                                                            \
            }                                                                \
        }                                                                    \
        float* op = opb + (size_t)(zz) * HW;                                 \
        _Pragma("unroll")                                                    \
        for (int oy = 0; oy < 4; ++oy) {                                     \
            v4f v = {acc[oy][0], acc[oy][1], acc[oy][2], acc[oy][3]};        \
            __builtin_nontemporal_store(v, (v4f*)(op + (size_t)oy * W));     \
        }                                                                    \
    }

    uint2 pfA[NCHK], pfB[NCHK];
    LOADPLANE(pfA, 0);
    if (zc > 1) LOADPLANE(pfB, 1);
    WRITEPLANE(regA, pfA);
    __syncthreads();

    for (int zz = 0; zz < zc; zz += 2) {
        // even plane: LDS regA holds zz; pfB holds zz+1 (in flight)
        if (zz + 2 < zc) LOADPLANE(pfA, zz + 2);   // issue 2 phases early
        COMPUTE(regA, zz);
        if (zz + 1 < zc) {
            WRITEPLANE(regB, pfB);                 // waits pfB (long cover)
            __syncthreads();
            // odd plane: LDS regB holds zz+1; pfA in flight for zz+2
            if (zz + 3 < zc) LOADPLANE(pfB, zz + 3);
            COMPUTE(regB, zz + 1);
            if (zz + 2 < zc) {
                WRITEPLANE(regA, pfA);
                __syncthreads();
            }
        }
    }
#undef COMPUTE
#undef LOADPLANE
#undef WRITEPLANE
}

// ---------------------------------------------------------------------------
extern "C" void kernel_launch(void* const* d_in, const int* in_sizes, int n_in,
                              void* d_out, int out_size, void* d_ws, size_t ws_size,
                              hipStream_t stream) {
    const float* x = (const float*)d_in[0];  // [128,1,512,512]
    const float* w = (const float*)d_in[1];  // [1,1,9,9]
    float* out = (float*)d_out;              // [128,1,512,512]

    unsigned int* wq = (unsigned int*)d_ws;                    // 64 u32 slot
    float* state = (float*)((char*)d_ws + 256);                // 2 fp32 planes
    unsigned short* Rbuf = (unsigned short*)(state + 2 * (size_t)HW);

    size_t head_b = 256 + 2 * (size_t)HW * sizeof(float);
    size_t plane_b = (size_t)HW * sizeof(unsigned short);
    int maxTc = 1;
    if (ws_size > head_b + plane_b)
        maxTc = (int)((ws_size - head_b) / plane_b);
    int Tc = T;
    if (Tc > maxTc) Tc = maxTc;
    if (Tc < 1) Tc = 1;

    for (int t0 = 0; t0 < T; t0 += Tc) {
        int tc = T - t0;
        if (tc > Tc) tc = Tc;
        scan_chunk<<<dim3(HW / 1024), 256, 0, stream>>>(
            x, (unsigned int*)Rbuf, state, w, wq, t0, tc);
        conv_chunk<<<dim3(W / BX, H / BY, (tc + ZP - 1) / ZP), 256, 0, stream>>>(
            Rbuf, wq, out, t0, tc);
    }
}